// Round 12
// baseline (297.555 us; speedup 1.0000x reference)
//
#include <hip/hip_runtime.h>
#include <stdint.h>

#define MDIM 8192
#define NDIM 4096
#define KDIM 4096
#define QBLK 128
#define KB 32   // KDIM / QBLK
#define NB 32   // NDIM / QBLK

// ---- 256x256 gemm, 8 waves, K-step 64, triple-buffered ----
#define BM 256
#define BN 256
#define BK 64
#define NSTEP (KDIM / BK)   // 64 K-steps
#define TILESZ (BM * BK)    // 16 KB per operand per K-step buffer

typedef __attribute__((ext_vector_type(4))) int int32x4;
typedef __attribute__((ext_vector_type(4))) float f32x4;

#define GPTR(p) ((const __attribute__((address_space(1))) void*)(p))
#define LPTR(p) ((__attribute__((address_space(3))) void*)(p))

__device__ __forceinline__ int quant1(float v, float s) {
  float q = rintf(v / s);
  q = fminf(fmaxf(q, -127.f), 127.f);
  return (int)q;
}

// ---------------- activation quant: one wave per (row m, kb-pair) ------------
__global__ __launch_bounds__(256) void quant_x_kernel(
    const float* __restrict__ x, int8_t* __restrict__ xq, float* __restrict__ xsT) {
  const int lane = threadIdx.x & 63;
  const int W = blockIdx.x * 4 + (threadIdx.x >> 6);
  const int m = W >> 4;
  const int p = W & 15;
  const int half = lane >> 5;
  const int l31 = lane & 31;
  const size_t base = (size_t)m * KDIM + (size_t)p * 256 + half * 128 + l31 * 4;

  const float4 v = *reinterpret_cast<const float4*>(x + base);
  float amax = fmaxf(fmaxf(fabsf(v.x), fabsf(v.y)), fmaxf(fabsf(v.z), fabsf(v.w)));
#pragma unroll
  for (int off = 16; off; off >>= 1)
    amax = fmaxf(amax, __shfl_xor(amax, off));
  const float scale = fmaxf(amax / 127.0f, 1e-12f);

  const int qa = quant1(v.x, scale);
  const int qb = quant1(v.y, scale);
  const int qc = quant1(v.z, scale);
  const int qd = quant1(v.w, scale);
  const uint32_t packed = (uint32_t)(qa & 0xff) | ((uint32_t)(qb & 0xff) << 8) |
                          ((uint32_t)(qc & 0xff) << 16) | ((uint32_t)(qd & 0xff) << 24);
  *reinterpret_cast<uint32_t*>(xq + base) = packed;
  if (l31 == 0) xsT[(size_t)(p * 2 + half) * MDIM + m] = scale;
}

// ---------------- weight quant: one 256-thread block per 128x128 block --------
__global__ __launch_bounds__(256) void quant_w_kernel(
    const float* __restrict__ w, int8_t* __restrict__ wq, float* __restrict__ ws) {
  const int nb = blockIdx.x >> 5;
  const int kb = blockIdx.x & 31;
  const int tid = threadIdx.x;
  const int lane = tid & 63;
  const int wv = tid >> 6;
  __shared__ float red[4];

  float amax = 0.f;
  float4 vals[16];
#pragma unroll
  for (int i = 0; i < 16; ++i) {
    const int idx4 = tid + i * 256;
    const int row = idx4 >> 5;
    const int c4 = idx4 & 31;
    const float4 v = *reinterpret_cast<const float4*>(
        w + (size_t)(nb * QBLK + row) * KDIM + (size_t)kb * QBLK + c4 * 4);
    vals[i] = v;
    amax = fmaxf(amax, fmaxf(fmaxf(fabsf(v.x), fabsf(v.y)),
                             fmaxf(fabsf(v.z), fabsf(v.w))));
  }
#pragma unroll
  for (int off = 32; off; off >>= 1)
    amax = fmaxf(amax, __shfl_xor(amax, off));
  if (lane == 0) red[wv] = amax;
  __syncthreads();
  amax = fmaxf(fmaxf(red[0], red[1]), fmaxf(red[2], red[3]));
  const float scale = fmaxf(amax / 127.0f, 1e-12f);

#pragma unroll
  for (int i = 0; i < 16; ++i) {
    const int idx4 = tid + i * 256;
    const int row = idx4 >> 5;
    const int c4 = idx4 & 31;
    const float4 v = vals[i];
    const int qa = quant1(v.x, scale);
    const int qb = quant1(v.y, scale);
    const int qc = quant1(v.z, scale);
    const int qd = quant1(v.w, scale);
    const uint32_t packed = (uint32_t)(qa & 0xff) | ((uint32_t)(qb & 0xff) << 8) |
                            ((uint32_t)(qc & 0xff) << 16) | ((uint32_t)(qd & 0xff) << 24);
    *reinterpret_cast<uint32_t*>(
        wq + (size_t)(nb * QBLK + row) * KDIM + (size_t)kb * QBLK + c4 * 4) = packed;
  }
  if (tid == 0) ws[nb * KB + kb] = scale;
}

// ---------------- int8 GEMM: 256x256, 8 waves, 4-phase/K-step interleave -----
// Per K-step (BK=64), 4 phases; phase q computes m-pair {2q,2q+1} x all 4 n.
// Each phase: {ds_read 2 af + 2 sx (+4 bf at q0); 1 stage gload; s_barrier;
// lgkmcnt(0)+sched_barrier; setprio(1) 8 MFMA setprio(0); fixup; s_barrier}.
// Triple-buffered K-step tiles (prefetch distance 2 => 4-phase load cover);
// vmcnt(4) once per K-step at end of phase 3 (certifies the tile staged two
// K-steps ago; the 4 fresh loads stay in flight -- never drains to 0).
// Swizzle for 64B rows: phys_chunk = chunk ^ ((row>>1)&3) -> 2-way max (free);
// lane-only on reads (rows step by 16) -> hoisted base + immediate offsets.
__global__ __launch_bounds__(512) void gemm_i8_kernel(
    const int8_t* __restrict__ Aq, const int8_t* __restrict__ Bq,
    const float* __restrict__ xsT, const float* __restrict__ wsp,
    const float* __restrict__ bias, float* __restrict__ C) {
  __shared__ int8_t As[3 * TILESZ];   // 48 KB
  __shared__ int8_t Bs[3 * TILESZ];   // 48 KB
  __shared__ float xsl[KB * BM];      // 32 KB, raw xs[kb][row]

  const int tid = threadIdx.x;
  const int lane = tid & 63;
  const int wid = tid >> 6;
  const int wm = wid >> 2;         // 0..1 -> 128 rows
  const int wn = wid & 3;          // 0..3 -> 64 cols
  const int l15 = lane & 15;
  const int lhi = lane >> 4;

  // XCD-chunked swizzle: 512 blocks, 8 XCDs x 64
  const int id = blockIdx.x;
  const int swz = (id & 7) * 64 + (id >> 3);
  const int bm = swz >> 4;
  const int bn = swz & 15;
  const int brow = bm * BM;
  const int bcol = bn * BN;
  const int nb2 = bn * 2 + (wn >> 1);

  f32x4 accf[8][4];
#pragma unroll
  for (int m = 0; m < 8; ++m)
#pragma unroll
    for (int n = 0; n < 4; ++n) accf[m][n] = (f32x4){0.f, 0.f, 0.f, 0.f};

  const int32x4 zeroc = {0, 0, 0, 0};

  // staging constants: tile = 1024 16B chunks (256 rows x 4), 512 thr x 2
  int ssrc[2], sdst[2];
#pragma unroll
  for (int g = 0; g < 2; ++g) {
    const int idx = g * 512 + tid;
    const int row = idx >> 2;
    const int c = idx & 3;
    ssrc[g] = row * KDIM + (c ^ ((row >> 1) & 3)) * 16;
    sdst[g] = idx * 16;
  }
  const int8_t* abase = Aq + (size_t)brow * KDIM;
  const int8_t* bbase = Bq + (size_t)bcol * KDIM;

  // fragment read bases (swizzle lane-only: (row>>1)&3 == (l15>>1)&3)
  const int swl = (l15 >> 1) & 3;
  const int a_rd = (wm * 128 + l15) * 64 + ((lhi ^ swl) * 16);   // + m*1024
  const int b_rd = (wn * 64 + l15) * 64 + ((lhi ^ swl) * 16);    // + n*1024
  const int x_rd = (wm * 128 + lhi * 4) * 4;                     // + m*64 + kb*1024
  const int8_t* xslb = reinterpret_cast<const int8_t*>(xsl);

#define LD4i(p) (*reinterpret_cast<const int32x4*>(p))
#define LD4f(p) (*reinterpret_cast<const f32x4*>(p))
#define GLOAD(src, dst) __builtin_amdgcn_global_load_lds(GPTR(src), LPTR(dst), 16, 0, 0)

#define PHASE(Q, CUR, STAGE_STMT, END_STMT)                                     \
  {                                                                             \
    const int32x4 af0 = LD4i(As + (CUR) * TILESZ + a_rd + (2 * (Q)) * 1024);    \
    const int32x4 af1 = LD4i(As + (CUR) * TILESZ + a_rd + (2 * (Q) + 1) * 1024);\
    const f32x4 sx0 = LD4f(xslb + kboff + x_rd + (2 * (Q)) * 64);               \
    const f32x4 sx1 = LD4f(xslb + kboff + x_rd + (2 * (Q) + 1) * 64);           \
    STAGE_STMT;                                                                 \
    asm volatile("s_barrier" ::: "memory");                                     \
    asm volatile("s_waitcnt lgkmcnt(0)" ::: "memory");                          \
    __builtin_amdgcn_sched_barrier(0);                                          \
    __builtin_amdgcn_s_setprio(1);                                              \
    const int32x4 p00 = __builtin_amdgcn_mfma_i32_16x16x64_i8(af0, bf[0], zeroc, 0, 0, 0); \
    const int32x4 p01 = __builtin_amdgcn_mfma_i32_16x16x64_i8(af0, bf[1], zeroc, 0, 0, 0); \
    const int32x4 p02 = __builtin_amdgcn_mfma_i32_16x16x64_i8(af0, bf[2], zeroc, 0, 0, 0); \
    const int32x4 p03 = __builtin_amdgcn_mfma_i32_16x16x64_i8(af0, bf[3], zeroc, 0, 0, 0); \
    const int32x4 p10 = __builtin_amdgcn_mfma_i32_16x16x64_i8(af1, bf[0], zeroc, 0, 0, 0); \
    const int32x4 p11 = __builtin_amdgcn_mfma_i32_16x16x64_i8(af1, bf[1], zeroc, 0, 0, 0); \
    const int32x4 p12 = __builtin_amdgcn_mfma_i32_16x16x64_i8(af1, bf[2], zeroc, 0, 0, 0); \
    const int32x4 p13 = __builtin_amdgcn_mfma_i32_16x16x64_i8(af1, bf[3], zeroc, 0, 0, 0); \
    __builtin_amdgcn_s_setprio(0);                                              \
    const f32x4 sxw0 = sx0 * swv;                                               \
    const f32x4 sxw1 = sx1 * swv;                                               \
    accf[2 * (Q)][0] += __builtin_convertvector(p00, f32x4) * sxw0;             \
    accf[2 * (Q)][1] += __builtin_convertvector(p01, f32x4) * sxw0;             \
    accf[2 * (Q)][2] += __builtin_convertvector(p02, f32x4) * sxw0;             \
    accf[2 * (Q)][3] += __builtin_convertvector(p03, f32x4) * sxw0;             \
    accf[2 * (Q) + 1][0] += __builtin_convertvector(p10, f32x4) * sxw1;         \
    accf[2 * (Q) + 1][1] += __builtin_convertvector(p11, f32x4) * sxw1;         \
    accf[2 * (Q) + 1][2] += __builtin_convertvector(p12, f32x4) * sxw1;         \
    accf[2 * (Q) + 1][3] += __builtin_convertvector(p13, f32x4) * sxw1;         \
    END_STMT;                                                                   \
    asm volatile("s_barrier" ::: "memory");                                     \
  }

#define KSTEP(S, CUR, NXT, LAST)                                                \
  {                                                                             \
    const int kb_ = (S) >> 1;                                                   \
    const int kboff = kb_ << 10;                                                \
    const float sw_ = wsp[nb2 * KB + kb_];                                      \
    const f32x4 swv = {sw_, sw_, sw_, sw_};                                     \
    const size_t kstg = (size_t)((S) + 2 < NSTEP ? (S) + 2 : NSTEP - 1) * BK;   \
    int32x4 bf[4];                                                              \
    _Pragma("unroll") for (int n = 0; n < 4; ++n)                               \
        bf[n] = LD4i(Bs + (CUR) * TILESZ + b_rd + n * 1024);                    \
    PHASE(0, CUR, GLOAD(abase + kstg + ssrc[0], As + (NXT) * TILESZ + sdst[0]), ;) \
    PHASE(1, CUR, GLOAD(abase + kstg + ssrc[1], As + (NXT) * TILESZ + sdst[1]), ;) \
    PHASE(2, CUR, GLOAD(bbase + kstg + ssrc[0], Bs + (NXT) * TILESZ + sdst[0]), ;) \
    PHASE(3, CUR, GLOAD(bbase + kstg + ssrc[1], Bs + (NXT) * TILESZ + sdst[1]),    \
          if (!(LAST)) { asm volatile("s_waitcnt vmcnt(4)" ::: "memory"); })    \
  }

  // ---- prologue: stage K-steps 0,1; fill xsl; full drain once ----
#pragma unroll
  for (int g = 0; g < 2; ++g) {
    GLOAD(abase + ssrc[g], As + sdst[g]);
    GLOAD(bbase + ssrc[g], Bs + sdst[g]);
  }
#pragma unroll
  for (int g = 0; g < 2; ++g) {
    GLOAD(abase + BK + ssrc[g], As + TILESZ + sdst[g]);
    GLOAD(bbase + BK + ssrc[g], Bs + TILESZ + sdst[g]);
  }
#pragma unroll
  for (int i = 0; i < 4; ++i) {
    const int idx = i * 512 + tid;        // 2048 f32x4 = 32 kb x 64 groups
    const int kb_ = idx >> 6;
    const int r4 = idx & 63;
    const f32x4 v = LD4f(xsT + (size_t)kb_ * MDIM + brow + r4 * 4);
    *reinterpret_cast<f32x4*>(xsl + kb_ * BM + r4 * 4) = v;
  }
  __syncthreads();

  // ---- main loop: 63 K-steps in x3-unrolled loop + peeled tail (s=63) ----
  for (int j = 0; j < 21; ++j) {
    const int s0 = j * 3;
    KSTEP(s0 + 0, 0, 2, 0)
    KSTEP(s0 + 1, 1, 0, 0)
    KSTEP(s0 + 2, 2, 1, 0)
  }
  KSTEP(63, 0, 2, 1)

  // ---- epilogue: bias + store f32 ----
  float bv[4];
  int coln[4];
#pragma unroll
  for (int n = 0; n < 4; ++n) {
    coln[n] = bcol + wn * 64 + n * 16 + l15;
    bv[n] = bias[coln[n]];
  }
#pragma unroll
  for (int m = 0; m < 8; ++m) {
#pragma unroll
    for (int r = 0; r < 4; ++r) {
      const int row = brow + wm * 128 + m * 16 + lhi * 4 + r;
#pragma unroll
      for (int n = 0; n < 4; ++n)
        C[(size_t)row * NDIM + coln[n]] = ((const float*)&accf[m][n])[r] + bv[n];
    }
  }
#undef PHASE
#undef KSTEP
#undef LD4i
#undef LD4f
#undef GLOAD
}

extern "C" void kernel_launch(void* const* d_in, const int* in_sizes, int n_in,
                              void* d_out, int out_size, void* d_ws, size_t ws_size,
                              hipStream_t stream) {
  const float* x = (const float*)d_in[0];
  const float* w = (const float*)d_in[1];
  const float* bias = (const float*)d_in[2];
  float* out = (float*)d_out;

  char* base = (char*)d_ws;
  size_t off = 0;
  int8_t* xq = (int8_t*)(base + off); off += (size_t)MDIM * KDIM;          // 32 MB
  int8_t* wq = (int8_t*)(base + off); off += (size_t)NDIM * KDIM;          // 16 MB
  float* xsT = (float*)(base + off); off += (size_t)KB * MDIM * 4;         // 1 MB
  float* wsc = (float*)(base + off);                                       // 4 KB

  quant_x_kernel<<<(MDIM * 16) / 4, 256, 0, stream>>>(x, xq, xsT);
  quant_w_kernel<<<NB * KB, 256, 0, stream>>>(w, wq, wsc);
  gemm_i8_kernel<<<(MDIM / BM) * (NDIM / BN), 512, 0, stream>>>(xq, wq, xsT, wsc, bias, out);
}

// Round 13
// 259.785 us; speedup vs baseline: 1.1454x; 1.1454x over previous
//
#include <hip/hip_runtime.h>
#include <stdint.h>

#define MDIM 8192
#define NDIM 4096
#define KDIM 4096
#define QBLK 128
#define KB 32   // KDIM / QBLK
#define NB 32   // NDIM / QBLK

#define BM 128
#define BN 128
#define BK 128

typedef __attribute__((ext_vector_type(4))) int int32x4;

#define GPTR(p) ((const __attribute__((address_space(1))) void*)(p))
#define LPTR(p) ((__attribute__((address_space(3))) void*)(p))

__device__ __forceinline__ int quant1(float v, float s) {
  float q = rintf(v / s);
  q = fminf(fmaxf(q, -127.f), 127.f);
  return (int)q;
}

// ---------------- activation quant: one wave per (row m, kb-pair) ------------
// lanes 0-31 cover quant block 2p, lanes 32-63 cover block 2p+1; float4/lane;
// amax reduce via shfl_xor within each 32-lane group.
__global__ __launch_bounds__(256) void quant_x_kernel(
    const float* __restrict__ x, int8_t* __restrict__ xq, float* __restrict__ xsT) {
  const int lane = threadIdx.x & 63;
  const int W = blockIdx.x * 4 + (threadIdx.x >> 6);   // global wave id
  const int m = W >> 4;          // row
  const int p = W & 15;          // kb pair
  const int half = lane >> 5;    // 0/1 -> kb = 2p + half
  const int l31 = lane & 31;
  const size_t base = (size_t)m * KDIM + (size_t)p * 256 + half * 128 + l31 * 4;

  const float4 v = *reinterpret_cast<const float4*>(x + base);
  float amax = fmaxf(fmaxf(fabsf(v.x), fabsf(v.y)), fmaxf(fabsf(v.z), fabsf(v.w)));
#pragma unroll
  for (int off = 16; off; off >>= 1)
    amax = fmaxf(amax, __shfl_xor(amax, off));
  const float scale = fmaxf(amax / 127.0f, 1e-12f);

  const int qa = quant1(v.x, scale);
  const int qb = quant1(v.y, scale);
  const int qc = quant1(v.z, scale);
  const int qd = quant1(v.w, scale);
  const uint32_t packed = (uint32_t)(qa & 0xff) | ((uint32_t)(qb & 0xff) << 8) |
                          ((uint32_t)(qc & 0xff) << 16) | ((uint32_t)(qd & 0xff) << 24);
  *reinterpret_cast<uint32_t*>(xq + base) = packed;
  if (l31 == 0) xsT[(size_t)(p * 2 + half) * MDIM + m] = scale;
}

// ---------------- weight quant: one 256-thread block per 128x128 block --------
__global__ __launch_bounds__(256) void quant_w_kernel(
    const float* __restrict__ w, int8_t* __restrict__ wq, float* __restrict__ ws) {
  const int nb = blockIdx.x >> 5;   // / KB
  const int kb = blockIdx.x & 31;   // % KB
  const int tid = threadIdx.x;
  const int lane = tid & 63;
  const int wv = tid >> 6;
  __shared__ float red[4];

  float amax = 0.f;
  float4 vals[16];
#pragma unroll
  for (int i = 0; i < 16; ++i) {
    const int idx4 = tid + i * 256;         // 4096 float4 per block
    const int row = idx4 >> 5;
    const int c4 = idx4 & 31;
    const float4 v = *reinterpret_cast<const float4*>(
        w + (size_t)(nb * QBLK + row) * KDIM + (size_t)kb * QBLK + c4 * 4);
    vals[i] = v;
    amax = fmaxf(amax, fmaxf(fmaxf(fabsf(v.x), fabsf(v.y)),
                             fmaxf(fabsf(v.z), fabsf(v.w))));
  }
#pragma unroll
  for (int off = 32; off; off >>= 1)
    amax = fmaxf(amax, __shfl_xor(amax, off));
  if (lane == 0) red[wv] = amax;
  __syncthreads();
  amax = fmaxf(fmaxf(red[0], red[1]), fmaxf(red[2], red[3]));
  const float scale = fmaxf(amax / 127.0f, 1e-12f);

#pragma unroll
  for (int i = 0; i < 16; ++i) {
    const int idx4 = tid + i * 256;
    const int row = idx4 >> 5;
    const int c4 = idx4 & 31;
    const float4 v = vals[i];
    const int qa = quant1(v.x, scale);
    const int qb = quant1(v.y, scale);
    const int qc = quant1(v.z, scale);
    const int qd = quant1(v.w, scale);
    const uint32_t packed = (uint32_t)(qa & 0xff) | ((uint32_t)(qb & 0xff) << 8) |
                            ((uint32_t)(qc & 0xff) << 16) | ((uint32_t)(qd & 0xff) << 24);
    *reinterpret_cast<uint32_t*>(
        wq + (size_t)(nb * QBLK + row) * KDIM + (size_t)kb * QBLK + c4 * 4) = packed;
  }
  if (tid == 0) ws[nb * KB + kb] = scale;
}

// ---------------- int8 blockwise GEMM (R3-exact structure + zero-C trick) ----
// LDS A/B tiles XOR-swizzled on 16B chunks: linear LDS dest + inverse-swizzled
// global source (global_load_lds writes linearly), swizzled ds_read address.
// MFMA i32_16x16x64_i8; kk=0 uses zeroc as C-in (no acc-init movs); scales
// read per-kb from L2-warm xsT as float4.
__global__ __launch_bounds__(256) void gemm_i8_kernel(
    const int8_t* __restrict__ Aq, const int8_t* __restrict__ Bq,
    const float* __restrict__ xsT, const float* __restrict__ wsp,
    const float* __restrict__ bias, float* __restrict__ C) {
  __shared__ int8_t As[BM * BK];      // 16 KB, swizzled
  __shared__ int8_t Bs[BN * BK];      // 16 KB, swizzled

  const int tid = threadIdx.x;
  const int lane = tid & 63;
  const int wv = tid >> 6;
  const int wr = wv >> 1;       // wave row 0..1
  const int wc = wv & 1;        // wave col 0..1
  const int l15 = lane & 15;
  const int lhi = lane >> 4;

  const int tiles_n = NDIM / BN;          // 32
  const int bm = blockIdx.x / tiles_n;
  const int bn = blockIdx.x % tiles_n;
  const int brow = bm * BM;
  const int bcol = bn * BN;

  float accf[4][4][4];
#pragma unroll
  for (int m = 0; m < 4; ++m)
#pragma unroll
    for (int n = 0; n < 4; ++n)
#pragma unroll
      for (int r = 0; r < 4; ++r) accf[m][n][r] = 0.f;

  const int32x4 zeroc = {0, 0, 0, 0};

  const int8_t* arow = Aq + (size_t)brow * KDIM;
  const int8_t* brp = Bq + (size_t)bcol * KDIM;

  for (int kb = 0; kb < KB; ++kb) {
    const int k0 = kb * BK;
#pragma unroll
    for (int i = 0; i < 4; ++i) {
      const int off = (i * 256 + tid) * 16;
      const int r = off >> 7;
      const int c = (off >> 4) & 7;
      const int csrc = c ^ (r & 7);
      __builtin_amdgcn_global_load_lds(GPTR(arow + (size_t)r * KDIM + k0 + csrc * 16),
                                       LPTR(As + off), 16, 0, 0);
    }
#pragma unroll
    for (int i = 0; i < 4; ++i) {
      const int off = (i * 256 + tid) * 16;
      const int r = off >> 7;
      const int c = (off >> 4) & 7;
      const int csrc = c ^ (r & 7);
      __builtin_amdgcn_global_load_lds(GPTR(brp + (size_t)r * KDIM + k0 + csrc * 16),
                                       LPTR(Bs + off), 16, 0, 0);
    }
    __syncthreads();

    // issue the scale loads early; L2-resident, covered by the MFMA phase
    float4 sx4[4];
#pragma unroll
    for (int m = 0; m < 4; ++m)
      sx4[m] = *reinterpret_cast<const float4*>(
          xsT + (size_t)kb * MDIM + brow + wr * 64 + m * 16 + lhi * 4);
    const float sw = wsp[bn * KB + kb];   // wave-uniform

    int32x4 acci[4][4];
    {
      const int cl = lhi;                      // kk=0 chunk
      int32x4 af[4], bf[4];
#pragma unroll
      for (int m = 0; m < 4; ++m) {
        const int rowA = wr * 64 + m * 16 + l15;
        af[m] = *reinterpret_cast<const int32x4*>(
            As + rowA * 128 + ((cl ^ (rowA & 7)) * 16));
      }
#pragma unroll
      for (int n = 0; n < 4; ++n) {
        const int rowB = wc * 64 + n * 16 + l15;
        bf[n] = *reinterpret_cast<const int32x4*>(
            Bs + rowB * 128 + ((cl ^ (rowB & 7)) * 16));
      }
#pragma unroll
      for (int m = 0; m < 4; ++m)
#pragma unroll
        for (int n = 0; n < 4; ++n)
          acci[m][n] = __builtin_amdgcn_mfma_i32_16x16x64_i8(af[m], bf[n], zeroc, 0, 0, 0);
    }
    {
      const int cl = 4 + lhi;                  // kk=1 chunk
      int32x4 af[4], bf[4];
#pragma unroll
      for (int m = 0; m < 4; ++m) {
        const int rowA = wr * 64 + m * 16 + l15;
        af[m] = *reinterpret_cast<const int32x4*>(
            As + rowA * 128 + ((cl ^ (rowA & 7)) * 16));
      }
#pragma unroll
      for (int n = 0; n < 4; ++n) {
        const int rowB = wc * 64 + n * 16 + l15;
        bf[n] = *reinterpret_cast<const int32x4*>(
            Bs + rowB * 128 + ((cl ^ (rowB & 7)) * 16));
      }
#pragma unroll
      for (int m = 0; m < 4; ++m)
#pragma unroll
        for (int n = 0; n < 4; ++n)
          acci[m][n] = __builtin_amdgcn_mfma_i32_16x16x64_i8(af[m], bf[n], acci[m][n], 0, 0, 0);
    }

#pragma unroll
    for (int m = 0; m < 4; ++m) {
#pragma unroll
      for (int r = 0; r < 4; ++r) {
        const float sx = ((const float*)&sx4[m])[r] * sw;
#pragma unroll
        for (int n = 0; n < 4; ++n)
          accf[m][n][r] += (float)acci[m][n][r] * sx;
      }
    }
    __syncthreads();
  }

  // epilogue: bias + store f32
#pragma unroll
  for (int m = 0; m < 4; ++m) {
#pragma unroll
    for (int r = 0; r < 4; ++r) {
      const int row = brow + wr * 64 + m * 16 + lhi * 4 + r;
#pragma unroll
      for (int n = 0; n < 4; ++n) {
        const int col = bcol + wc * 64 + n * 16 + l15;
        C[(size_t)row * NDIM + col] = accf[m][n][r] + bias[col];
      }
    }
  }
}

extern "C" void kernel_launch(void* const* d_in, const int* in_sizes, int n_in,
                              void* d_out, int out_size, void* d_ws, size_t ws_size,
                              hipStream_t stream) {
  const float* x = (const float*)d_in[0];
  const float* w = (const float*)d_in[1];
  const float* bias = (const float*)d_in[2];
  float* out = (float*)d_out;

  char* base = (char*)d_ws;
  size_t off = 0;
  int8_t* xq = (int8_t*)(base + off); off += (size_t)MDIM * KDIM;          // 32 MB
  int8_t* wq = (int8_t*)(base + off); off += (size_t)NDIM * KDIM;          // 16 MB
  float* xsT = (float*)(base + off); off += (size_t)KB * MDIM * 4;         // 1 MB
  float* wsc = (float*)(base + off);                                       // 4 KB

  quant_x_kernel<<<(MDIM * 16) / 4, 256, 0, stream>>>(x, xq, xsT);
  quant_w_kernel<<<NB * KB, 256, 0, stream>>>(w, wq, wsc);
  gemm_i8_kernel<<<(MDIM / BM) * (NDIM / BN), 256, 0, stream>>>(xq, wq, xsT, wsc, bias, out);
}